// Round 3
// baseline (694.713 us; speedup 1.0000x reference)
//
#include <hip/hip_runtime.h>

#define L_DIM 4096
#define B_DIM 4
#define KNN 48
#define BIGF 1000000000.0f

// ---------------------------------------------------------------------------
// prep: compact CA coords + |x|^2 into float4, copy mask, count valid/batch
// x2 uses the SAME contracted-FMA chain as the einsum dot (XLA:CPU compiles
// with FP contraction on): x2 = fma(z,z, fma(y,y, x*x)). This also makes
// dot(i,i) bit-equal to x2(i) => D[i,i] == 0 exactly, as in the reference.
// ---------------------------------------------------------------------------
__global__ __launch_bounds__(256) void prep_kernel(const float* __restrict__ X,
                                                   const float* __restrict__ mask,
                                                   float4* __restrict__ c4,
                                                   float* __restrict__ mf,
                                                   int* __restrict__ nvalid) {
#pragma clang fp contract(off)
    int i = blockIdx.x * 256 + threadIdx.x;              // i in [0, B*L)
    const float* p = X + (size_t)i * 12 + 3;             // atom 1 (CA) of residue i
    float x = p[0], y = p[1], z = p[2];
    float x2 = __builtin_fmaf(z, z, __builtin_fmaf(y, y, x * x));
    c4[i] = make_float4(x, y, z, x2);
    float m = mask[i];
    mf[i] = m;
    if (m > 0.0f) atomicAdd(&nvalid[i >> 12], 1);        // i>>12 == batch index
}

// ---------------------------------------------------------------------------
// main: one block per (b,i) row. 256 threads.
//   phase A: each thread computes 16 distances -> u64 keys (bits(Dm)<<32)|j
//            dot = fma(z,z', fma(y,y', x*x')) (ascending d, contracted)
//   phase B: per-thread register bitonic sort of 16 keys
//   phase C: per-wave 48 pops (k-way merge of 64 sorted lists via shfl-min)
//   phase D: wave 0 rank-merges 4 sorted 48-lists, writes top-48 in order
// ---------------------------------------------------------------------------
__global__ __launch_bounds__(256) void knn_kernel(const float4* __restrict__ c4,
                                                  const float* __restrict__ mf,
                                                  const int* __restrict__ nvalid,
                                                  float* __restrict__ dn,
                                                  float* __restrict__ ei) {
    __shared__ unsigned long long lists[256 * 17];   // padded stride 17: 2-way banks
    __shared__ unsigned long long wout[4 * KNN];

    const int row = blockIdx.x;                // b*L + i
    const int b = row >> 12;
    const int i = row & (L_DIM - 1);
    const int t = threadIdx.x;

    float* dnrow = dn + (size_t)row * KNN;
    float* eirow = ei + (size_t)row * KNN;

    // degenerate batch (n_valid<=K) or invalid query row -> self-fill, D=0
    const bool degen = (nvalid[b] <= KNN);
    const bool invalid = !(mf[row] > 0.0f);
    if (degen || invalid) {                    // block-uniform branch
        if (t < KNN) { dnrow[t] = 0.0f; eirow[t] = (float)i; }
        return;
    }

    // ---- phase A: distances + key build ----
    unsigned long long v[16];
    {
#pragma clang fp contract(off)
        const float4 q = c4[(size_t)b * L_DIM + i];
        const float4* cb = c4 + (size_t)b * L_DIM;
        const float* mb = mf + (size_t)b * L_DIM;
#pragma unroll
        for (int it = 0; it < 16; ++it) {
            int j = it * 256 + t;
            float4 pj = cb[j];
            float mk = mb[j];
            // contracted dot, ascending d: fma(z, z', fma(y, y', x*x'))
            float dot = __builtin_fmaf(pj.z, q.z,
                        __builtin_fmaf(pj.y, q.y, pj.x * q.x));
            float d2 = (q.w + pj.w) - 2.0f * dot;   // add rounded; 2*dot exact; sub rounded
            float d = sqrtf(fmaxf(d2, 0.0f));
            float dm = (mk > 0.0f) ? d : BIGF;
            v[it] = ((unsigned long long)__float_as_uint(dm) << 32) | (unsigned)j;
        }
    }

    // ---- phase B: register bitonic sort, ascending (value, then index) ----
#pragma unroll
    for (int kk = 2; kk <= 16; kk <<= 1) {
#pragma unroll
        for (int jj = kk >> 1; jj > 0; jj >>= 1) {
#pragma unroll
            for (int ii = 0; ii < 16; ++ii) {
                int ll = ii ^ jj;
                if (ll > ii) {
                    bool up = ((ii & kk) == 0);
                    unsigned long long a = v[ii], c = v[ll];
                    bool sw = up ? (a > c) : (a < c);
                    if (sw) { v[ii] = c; v[ll] = a; }
                }
            }
        }
    }

#pragma unroll
    for (int r = 0; r < 16; ++r) lists[t * 17 + r] = v[r];

    unsigned long long head = v[0];
    int ptr = 1;
    const int w = t >> 6;

    // ---- phase C: 48 pops per wave (64-list merge). Keys are unique (j
    // embedded) so exactly one winner per pop; only the winner touches LDS. ----
    for (int k = 0; k < KNN; ++k) {
        unsigned long long m = head;
#pragma unroll
        for (int s = 1; s < 64; s <<= 1) {
            unsigned long long o = __shfl_xor(m, s);
            m = (o < m) ? o : m;
        }
        if (head == m) {
            wout[w * KNN + k] = m;
            head = (ptr < 16) ? lists[t * 17 + ptr] : ~0ULL;
            ++ptr;
        }
    }

    __syncthreads();

    // ---- phase D: rank-merge 4 sorted lists of 48 -> global top-48 ----
    if (t < 64) {
        for (int c = t; c < 4 * KNN; c += 64) {
            unsigned long long key = wout[c];
            int wsrc = c / KNN;
            int p = c - wsrc * KNN;
            int rank = p;
            for (int w2 = 0; w2 < 4; ++w2) {
                if (w2 == wsrc) continue;
                int lo = 0, hi = KNN;                 // lower_bound(count < key)
                while (lo < hi) {
                    int mid = (lo + hi) >> 1;
                    if (wout[w2 * KNN + mid] < key) lo = mid + 1; else hi = mid;
                }
                rank += lo;
            }
            if (rank < KNN) {
                dnrow[rank] = __uint_as_float((unsigned)(key >> 32));
                eirow[rank] = (float)(key & 0xFFFFFFFFULL);
            }
        }
    }
}

extern "C" void kernel_launch(void* const* d_in, const int* in_sizes, int n_in,
                              void* d_out, int out_size, void* d_ws, size_t ws_size,
                              hipStream_t stream) {
    const float* X = (const float*)d_in[0];
    const float* mask = (const float*)d_in[1];
    // d_in[2] = k_neighbors (always 48 for this problem; out_size confirms)

    float* out = (float*)d_out;
    float* dn = out;                                   // (B,L,K) D_neighbors
    float* ei = out + (size_t)B_DIM * L_DIM * KNN;     // (B,L,K) E_idx as f32

    char* ws = (char*)d_ws;
    float4* c4 = (float4*)ws;                                          // 256 KiB
    float* mf = (float*)(ws + (size_t)B_DIM * L_DIM * 16);             //  64 KiB
    int* nv = (int*)(ws + (size_t)B_DIM * L_DIM * 16 + (size_t)B_DIM * L_DIM * 4);

    hipMemsetAsync(nv, 0, B_DIM * sizeof(int), stream);
    prep_kernel<<<(B_DIM * L_DIM) / 256, 256, 0, stream>>>(X, mask, c4, mf, nv);
    knn_kernel<<<B_DIM * L_DIM, 256, 0, stream>>>(c4, mf, nv, dn, ei);
}

// Round 4
// 325.364 us; speedup vs baseline: 2.1352x; 2.1352x over previous
//
#include <hip/hip_runtime.h>

#define L_DIM 4096
#define B_DIM 4
#define KNN 48
#define BIGF 1000000000.0f
#define CAP 1536   // survivor cap; data needs ~50, 1536 is absurd headroom

// ---------------------------------------------------------------------------
// prep: compact CA coords + |x|^2 into float4, copy mask, count valid/batch
// x2 uses the contracted-FMA chain (matches XLA:CPU fused codegen); also makes
// dot(i,i) bit-equal to x2(i) => D[i,i] == 0 exactly.
// ---------------------------------------------------------------------------
__global__ __launch_bounds__(256) void prep_kernel(const float* __restrict__ X,
                                                   const float* __restrict__ mask,
                                                   float4* __restrict__ c4,
                                                   float* __restrict__ mf,
                                                   int* __restrict__ nvalid) {
#pragma clang fp contract(off)
    int i = blockIdx.x * 256 + threadIdx.x;              // i in [0, B*L)
    const float* p = X + (size_t)i * 12 + 3;             // atom 1 (CA)
    float x = p[0], y = p[1], z = p[2];
    float x2 = __builtin_fmaf(z, z, __builtin_fmaf(y, y, x * x));
    c4[i] = make_float4(x, y, z, x2);
    float m = mask[i];
    mf[i] = m;
    if (m > 0.0f) atomicAdd(&nvalid[i >> 12], 1);
}

// ---------------------------------------------------------------------------
// main: one block per (b,i) row, 256 threads, 16 candidates/thread.
//  A: distances -> u32 bits in registers (positive floats are bit-monotone)
//  B: per-thread min; wave bitonic sort of the 64 minima; T_w = lane 47.
//     Proof T_w >= d48: fewer than 48 values are < d48, so fewer than 48
//     thread-minima in any wave are < d48. T = min over waves, still >= d48.
//  C: rescan 16 regs, push keys (bits<<32|j) <= T to compact LDS list (~50)
//  D: rank-count survivors (exact (value,index) order = lax.top_k tie-break),
//     scatter top-48 straight to output slots.
// ---------------------------------------------------------------------------
__global__ __launch_bounds__(256) void knn_kernel(const float4* __restrict__ c4,
                                                  const float* __restrict__ mf,
                                                  const int* __restrict__ nvalid,
                                                  float* __restrict__ dn,
                                                  float* __restrict__ ei) {
    __shared__ unsigned long long surv[CAP];
    __shared__ unsigned tminw[4];
    __shared__ int cnt;

    const int row = blockIdx.x;                // b*L + i
    const int b = row >> 12;
    const int i = row & (L_DIM - 1);
    const int t = threadIdx.x;
    const int lane = t & 63;

    float* dnrow = dn + (size_t)row * KNN;
    float* eirow = ei + (size_t)row * KNN;

    const bool degen = (nvalid[b] <= KNN);
    const bool invalid = !(mf[row] > 0.0f);
    if (degen || invalid) {                    // block-uniform branch
        if (t < KNN) { dnrow[t] = 0.0f; eirow[t] = (float)i; }
        return;
    }

    // ---- A: distances (bit patterns) ----
    unsigned db[16];
    {
#pragma clang fp contract(off)
        const float4 q = c4[(size_t)b * L_DIM + i];
        const float4* cb = c4 + (size_t)b * L_DIM;
        const float* mb = mf + (size_t)b * L_DIM;
#pragma unroll
        for (int it = 0; it < 16; ++it) {
            int j = it * 256 + t;
            float4 pj = cb[j];
            float mk = mb[j];
            float dot = __builtin_fmaf(pj.z, q.z,
                        __builtin_fmaf(pj.y, q.y, pj.x * q.x));
            float d2 = (q.w + pj.w) - 2.0f * dot;
            float d = sqrtf(fmaxf(d2, 0.0f));
            float dm = (mk > 0.0f) ? d : BIGF;
            db[it] = __float_as_uint(dm);
        }
    }

    // ---- B: threshold T >= d48 ----
    unsigned sv = db[0];
#pragma unroll
    for (int it = 1; it < 16; ++it) sv = min(sv, db[it]);
#pragma unroll
    for (int k = 2; k <= 64; k <<= 1) {
#pragma unroll
        for (int j = k >> 1; j > 0; j >>= 1) {
            unsigned o = __shfl_xor(sv, j);
            unsigned mn = min(sv, o), mx = max(sv, o);
            bool asc = ((lane & k) == 0);
            bool low = ((lane & j) == 0);
            sv = (asc == low) ? mn : mx;
        }
    }
    unsigned Tw = __shfl(sv, 47);              // wave's 48th-smallest minimum
    if (t == 0) cnt = 0;
    if (lane == 0) tminw[t >> 6] = Tw;
    __syncthreads();
    unsigned T = min(min(tminw[0], tminw[1]), min(tminw[2], tminw[3]));

    // ---- C: compact survivors ----
#pragma unroll
    for (int it = 0; it < 16; ++it) {
        if (db[it] <= T) {
            int pos = atomicAdd(&cnt, 1);
            if (pos < CAP) {
                unsigned j = (unsigned)(it * 256 + t);
                surv[pos] = ((unsigned long long)db[it] << 32) | j;
            }
        }
    }
    __syncthreads();

    // ---- D: exact rank among survivors, scatter top-48 ----
    int S = cnt; if (S > CAP) S = CAP;
    for (int c = t; c < S; c += 256) {
        unsigned long long key = surv[c];
        int rank = 0;
        for (int s = 0; s < S; ++s) rank += (surv[s] < key);  // broadcast reads
        if (rank < KNN) {
            dnrow[rank] = __uint_as_float((unsigned)(key >> 32));
            eirow[rank] = (float)(key & 0xFFFFFFFFULL);
        }
    }
}

extern "C" void kernel_launch(void* const* d_in, const int* in_sizes, int n_in,
                              void* d_out, int out_size, void* d_ws, size_t ws_size,
                              hipStream_t stream) {
    const float* X = (const float*)d_in[0];
    const float* mask = (const float*)d_in[1];

    float* out = (float*)d_out;
    float* dn = out;                                   // (B,L,K) D_neighbors
    float* ei = out + (size_t)B_DIM * L_DIM * KNN;     // (B,L,K) E_idx as f32

    char* ws = (char*)d_ws;
    float4* c4 = (float4*)ws;                                          // 256 KiB
    float* mf = (float*)(ws + (size_t)B_DIM * L_DIM * 16);             //  64 KiB
    int* nv = (int*)(ws + (size_t)B_DIM * L_DIM * 16 + (size_t)B_DIM * L_DIM * 4);

    hipMemsetAsync(nv, 0, B_DIM * sizeof(int), stream);
    prep_kernel<<<(B_DIM * L_DIM) / 256, 256, 0, stream>>>(X, mask, c4, mf, nv);
    knn_kernel<<<B_DIM * L_DIM, 256, 0, stream>>>(c4, mf, nv, dn, ei);
}

// Round 5
// 154.852 us; speedup vs baseline: 4.4863x; 2.1011x over previous
//
#include <hip/hip_runtime.h>

#define L_DIM 4096
#define B_DIM 4
#define KNN 48
#define CAP 1536          // survivor cap; data needs ~50-60
#define INVALID_X2 1.0e30f   // encodes mask=0: d ~ 1e15, never selectable

// ---------------------------------------------------------------------------
// prep: compact CA coords + |x|^2 into float4. Mask folded into w:
//   w = valid ? x2 : 1e30. No atomics, no side arrays.
// x2 uses the contracted-FMA chain (matches XLA:CPU fused codegen); makes
// dot(i,i) bit-equal to x2(i) => D[i,i] == 0 exactly.
// ---------------------------------------------------------------------------
__global__ __launch_bounds__(256) void prep_kernel(const float* __restrict__ X,
                                                   const float* __restrict__ mask,
                                                   float4* __restrict__ c4) {
#pragma clang fp contract(off)
    int i = blockIdx.x * 256 + threadIdx.x;              // i in [0, B*L)
    const float4* X4 = (const float4*)X;                 // residue = 3 aligned float4
    float4 a = X4[3 * i];                                // f0 f1 f2 | f3(=CA x)
    float4 bb = X4[3 * i + 1];                           // f4(=CA y) f5(=CA z) ...
    float x = a.w, y = bb.x, z = bb.y;
    float x2 = __builtin_fmaf(z, z, __builtin_fmaf(y, y, x * x));
    float m = mask[i];
    c4[i] = make_float4(x, y, z, (m > 0.0f) ? x2 : INVALID_X2);
}

// ---------------------------------------------------------------------------
// main: one block per (b,i) row, 256 threads, 16 candidates/thread.
//  A: distances -> u32 bits in registers (positive floats are bit-monotone);
//     invalid candidates come out at ~1e15 automatically (w=1e30).
//  A': n_valid = count(d < 1e12) via shuffle+LDS reduce (exact: real d << 1e12,
//      invalid d ~ 1e15). Early self-fill for degen batch / invalid row.
//  B: per-thread min; wave bitonic sort of 64 minima; T = min over waves of
//     48th-smallest (provably >= d48).
//  C: compact survivors (d <= T) into LDS (~50-60 keys).
//  D: rank-count survivors (exact (value,index) order = lax.top_k tie-break),
//     scatter top-48 straight to output slots.
// ---------------------------------------------------------------------------
__global__ __launch_bounds__(256) void knn_kernel(const float4* __restrict__ c4,
                                                  const float* __restrict__ mask,
                                                  float* __restrict__ dn,
                                                  float* __restrict__ ei) {
    __shared__ unsigned long long surv[CAP];
    __shared__ unsigned tminw[4];
    __shared__ int nvw[4];
    __shared__ int cnt;

    const int row = blockIdx.x;                // b*L + i
    const int b = row >> 12;
    const int i = row & (L_DIM - 1);
    const int t = threadIdx.x;
    const int lane = t & 63;

    float* dnrow = dn + (size_t)row * KNN;
    float* eirow = ei + (size_t)row * KNN;

    // invalid query row -> self-fill (block-uniform branch)
    if (!(mask[row] > 0.0f)) {
        if (t < KNN) { dnrow[t] = 0.0f; eirow[t] = (float)i; }
        return;
    }

    // ---- A: distances (bit patterns) ----
    unsigned db[16];
    {
#pragma clang fp contract(off)
        const float4 q = c4[(size_t)b * L_DIM + i];      // q.w = x2_i (row valid)
        const float4* cb = c4 + (size_t)b * L_DIM;
#pragma unroll
        for (int it = 0; it < 16; ++it) {
            int j = it * 256 + t;
            float4 pj = cb[j];
            float dot = __builtin_fmaf(pj.z, q.z,
                        __builtin_fmaf(pj.y, q.y, pj.x * q.x));
            float d2 = (q.w + pj.w) - 2.0f * dot;
            float d = sqrtf(fmaxf(d2, 0.0f));
            db[it] = __float_as_uint(d);
        }
    }

    // ---- A': n_valid (count d < 1e12; valid<=~1e3, invalid ~1e15) ----
    {
        const unsigned VTH = __float_as_uint(1.0e12f);
        int nvt = 0;
#pragma unroll
        for (int it = 0; it < 16; ++it) nvt += (db[it] < VTH) ? 1 : 0;
#pragma unroll
        for (int s = 1; s < 64; s <<= 1) nvt += __shfl_xor(nvt, s);
        if (lane == 0) nvw[t >> 6] = nvt;
        if (t == 0) cnt = 0;
    }
    __syncthreads();
    {
        int nvalid = nvw[0] + nvw[1] + nvw[2] + nvw[3];
        if (nvalid <= KNN) {                   // degenerate batch, block-uniform
            if (t < KNN) { dnrow[t] = 0.0f; eirow[t] = (float)i; }
            return;
        }
    }

    // ---- B: threshold T >= d48 (wave bitonic sort of per-thread minima) ----
    unsigned sv = db[0];
#pragma unroll
    for (int it = 1; it < 16; ++it) sv = min(sv, db[it]);
#pragma unroll
    for (int k = 2; k <= 64; k <<= 1) {
#pragma unroll
        for (int j = k >> 1; j > 0; j >>= 1) {
            unsigned o = __shfl_xor(sv, j);
            unsigned mn = min(sv, o), mx = max(sv, o);
            bool asc = ((lane & k) == 0);
            bool low = ((lane & j) == 0);
            sv = (asc == low) ? mn : mx;
        }
    }
    unsigned Tw = __shfl(sv, 47);              // wave's 48th-smallest minimum
    if (lane == 0) tminw[t >> 6] = Tw;
    __syncthreads();
    unsigned T = min(min(tminw[0], tminw[1]), min(tminw[2], tminw[3]));

    // ---- C: compact survivors ----
#pragma unroll
    for (int it = 0; it < 16; ++it) {
        if (db[it] <= T) {
            int pos = atomicAdd(&cnt, 1);      // LDS atomic
            if (pos < CAP) {
                unsigned j = (unsigned)(it * 256 + t);
                surv[pos] = ((unsigned long long)db[it] << 32) | j;
            }
        }
    }
    __syncthreads();

    // ---- D: exact rank among survivors, scatter top-48 ----
    int S = cnt; if (S > CAP) S = CAP;
    for (int c = t; c < S; c += 256) {
        unsigned long long key = surv[c];
        int rank = 0;
        for (int s = 0; s < S; ++s) rank += (surv[s] < key);  // broadcast reads
        if (rank < KNN) {
            dnrow[rank] = __uint_as_float((unsigned)(key >> 32));
            eirow[rank] = (float)(key & 0xFFFFFFFFULL);
        }
    }
}

extern "C" void kernel_launch(void* const* d_in, const int* in_sizes, int n_in,
                              void* d_out, int out_size, void* d_ws, size_t ws_size,
                              hipStream_t stream) {
    const float* X = (const float*)d_in[0];
    const float* mask = (const float*)d_in[1];

    float* out = (float*)d_out;
    float* dn = out;                                   // (B,L,K) D_neighbors
    float* ei = out + (size_t)B_DIM * L_DIM * KNN;     // (B,L,K) E_idx as f32

    float4* c4 = (float4*)d_ws;                        // 256 KiB scratch

    prep_kernel<<<(B_DIM * L_DIM) / 256, 256, 0, stream>>>(X, mask, c4);
    knn_kernel<<<B_DIM * L_DIM, 256, 0, stream>>>(c4, mask, dn, ei);
}